// Round 19
// baseline (159.371 us; speedup 1.0000x reference)
//
#include <hip/hip_runtime.h>
#include <cstdint>
#include <cstddef>

typedef unsigned short ushort_t;
typedef signed char s8;
typedef __attribute__((ext_vector_type(4))) float f32x4;
typedef __attribute__((ext_vector_type(16))) float f32x16;
typedef __attribute__((ext_vector_type(8))) short short8;
typedef __attribute__((ext_vector_type(4))) float float4_t;
typedef __attribute__((ext_vector_type(4))) unsigned short ushort4_t;
typedef __attribute__((ext_vector_type(2))) unsigned int uint2v;
typedef __attribute__((ext_vector_type(4))) int int4v;
typedef __attribute__((ext_vector_type(2))) int int2v;

#define KD 2048     // inner dim of both GEMMs
#define TT 2048     // sequence length T
#define NH 32       // heads
#define NG 8        // kv groups

__device__ __forceinline__ ushort_t f2bf(float f) {
  union { float f; uint32_t u; } cv; cv.f = f;
  uint32_t u = cv.u;
  return (ushort_t)((u + 0x7FFFu + ((u >> 16) & 1u)) >> 16);
}

__device__ __forceinline__ float bf2f(ushort_t v) {
  union { uint32_t u; float f; } cv; cv.u = ((uint32_t)v) << 16;
  return cv.f;
}

__device__ __forceinline__ uint32_t cvtpk(float a, float b) {
  uint32_t r;
  asm("v_cvt_pk_bf16_f32 %0, %1, %2" : "=v"(r) : "v"(a), "v"(b));
  return r;
}

__device__ __forceinline__ float exp2fast(float x) {
  float r;
  asm("v_exp_f32 %0, %1" : "=v"(r) : "v"(x));
  return r;
}

__device__ __forceinline__ float max3f(float a, float b, float c) {
  return fmaxf(fmaxf(a, b), c);   // clang fuses to v_max3_f32
}

__device__ __forceinline__ void gload_lds16(const void* g, void* l) {
  __builtin_amdgcn_global_load_lds(
      (const __attribute__((address_space(1))) unsigned int*)g,
      (__attribute__((address_space(3))) unsigned int*)l, 16, 0, 0);
}

// ---- prep1: xq (bid<4096) + weight f32->bf16 transpose (bid>=4096) --------
__global__ __launch_bounds__(256) void prep1_kernel(const float* __restrict__ x,
                                                    s8* __restrict__ xq,
                                                    float* __restrict__ xs,
                                                    const float* __restrict__ Wq,
                                                    const float* __restrict__ Wk,
                                                    const float* __restrict__ Wv,
                                                    const float* __restrict__ Wo,
                                                    ushort_t* __restrict__ wqkvT,
                                                    ushort_t* __restrict__ woT) {
  const int tid = threadIdx.x;
  if (blockIdx.x < 4096) {
    const int row = blockIdx.x;
    const float* src = x + (size_t)row * 2048 + tid * 8;
    float4_t a = *(const float4_t*)(src);
    float4_t b = *(const float4_t*)(src + 4);
    float m = fmaxf(fmaxf(fmaxf(fabsf(a[0]), fabsf(a[1])), fmaxf(fabsf(a[2]), fabsf(a[3]))),
                    fmaxf(fmaxf(fabsf(b[0]), fabsf(b[1])), fmaxf(fabsf(b[2]), fabsf(b[3]))));
#pragma unroll
    for (int st = 32; st > 0; st >>= 1) m = fmaxf(m, __shfl_xor(m, st));
    __shared__ float red[4];
    if ((tid & 63) == 0) red[tid >> 6] = m;
    __syncthreads();
    m = fmaxf(fmaxf(red[0], red[1]), fmaxf(red[2], red[3]));
    const float inv = (m > 0.f) ? 127.f / m : 0.f;
    union { s8 c[8]; int2v v; } pk;
#pragma unroll
    for (int i = 0; i < 4; ++i) {
      pk.c[i]     = (s8)__float2int_rn(a[i] * inv);
      pk.c[4 + i] = (s8)__float2int_rn(b[i] * inv);
    }
    *(int2v*)(xq + (size_t)row * 2048 + tid * 8) = pk.v;
    if (tid == 0) xs[row] = (m > 0.f) ? m / 127.f : 0.f;
    return;
  }
  // weight transpose part
  __shared__ float tile[32][33];
  const int bid = blockIdx.x - 4096;
  const float* src;
  ushort_t* dst;
  int Nc, bx, by;
  if (bid < 4096)      { src = Wq; dst = wqkvT;                       Nc = 2048; int r = bid;        bx = r & 63; by = r >> 6; }
  else if (bid < 5120) { src = Wk; dst = wqkvT + (size_t)2048 * KD;   Nc = 512;  int r = bid - 4096; bx = r & 15; by = r >> 4; }
  else if (bid < 6144) { src = Wv; dst = wqkvT + (size_t)2560 * KD;   Nc = 512;  int r = bid - 5120; bx = r & 15; by = r >> 4; }
  else                 { src = Wo; dst = woT;                         Nc = 2048; int r = bid - 6144; bx = r & 63; by = r >> 6; }
  const int tx = tid & 31, ty = tid >> 5;
  const int c0 = bx * 32, r0 = by * 32;
#pragma unroll
  for (int i = 0; i < 4; i++)
    tile[ty + i * 8][tx] = src[(size_t)(r0 + ty + i * 8) * Nc + c0 + tx];
  __syncthreads();
#pragma unroll
  for (int i = 0; i < 4; i++)
    dst[(size_t)(c0 + ty + i * 8) * KD + r0 + tx] = f2bf(tile[tx][ty + i * 8]);
}

// ------- wqall: both weight-quant passes, one launch -----------------------
__global__ __launch_bounds__(256) void wqall_kernel(const ushort_t* __restrict__ wqkvT,
                                                    const ushort_t* __restrict__ woT,
                                                    s8* __restrict__ wq_q,
                                                    s8* __restrict__ wo_q,
                                                    float* __restrict__ wqs,
                                                    float* __restrict__ wos) {
  const int bid = blockIdx.x;
  const ushort_t* wt;
  s8* wq;
  float* sc;
  int row;
  if (bid < 3072) { wt = wqkvT; wq = wq_q; sc = wqs; row = bid; }
  else            { wt = woT;   wq = wo_q; sc = wos; row = bid - 3072; }
  const int tid = threadIdx.x;
  short8 v8 = *(const short8*)(wt + (size_t)row * 2048 + tid * 8);
  float f[8];
#pragma unroll
  for (int i = 0; i < 8; ++i) f[i] = bf2f((ushort_t)v8[i]);
  float m = 0.f;
#pragma unroll
  for (int i = 0; i < 8; ++i) m = fmaxf(m, fabsf(f[i]));
#pragma unroll
  for (int st = 32; st > 0; st >>= 1) m = fmaxf(m, __shfl_xor(m, st));
  __shared__ float red[4];
  if ((tid & 63) == 0) red[tid >> 6] = m;
  __syncthreads();
  m = fmaxf(fmaxf(red[0], red[1]), fmaxf(red[2], red[3]));
  const float inv = (m > 0.f) ? 127.f / m : 0.f;
  union { s8 c[8]; int2v v; } pk;
#pragma unroll
  for (int i = 0; i < 8; ++i) pk.c[i] = (s8)__float2int_rn(f[i] * inv);
  *(int2v*)(wq + (size_t)row * 2048 + tid * 8) = pk.v;
  if (tid == 0) sc[row] = (m > 0.f) ? m / 127.f : 0.f;
}

// ------- generic bf16 [rows][2048] -> i8 per-row-scaled (attn out) ---------
__global__ __launch_bounds__(256) void wq_kernel(const ushort_t* __restrict__ wt,
                                                 s8* __restrict__ wq,
                                                 float* __restrict__ wqs) {
  const int row = blockIdx.x;
  const int tid = threadIdx.x;
  short8 v8 = *(const short8*)(wt + (size_t)row * 2048 + tid * 8);
  float f[8];
#pragma unroll
  for (int i = 0; i < 8; ++i) f[i] = bf2f((ushort_t)v8[i]);
  float m = 0.f;
#pragma unroll
  for (int i = 0; i < 8; ++i) m = fmaxf(m, fabsf(f[i]));
#pragma unroll
  for (int st = 32; st > 0; st >>= 1) m = fmaxf(m, __shfl_xor(m, st));
  __shared__ float red[4];
  if ((tid & 63) == 0) red[tid >> 6] = m;
  __syncthreads();
  m = fmaxf(fmaxf(red[0], red[1]), fmaxf(red[2], red[3]));
  const float inv = (m > 0.f) ? 127.f / m : 0.f;
  union { s8 c[8]; int2v v; } pk;
#pragma unroll
  for (int i = 0; i < 8; ++i) pk.c[i] = (s8)__float2int_rn(f[i] * inv);
  *(int2v*)(wq + (size_t)row * 2048 + tid * 8) = pk.v;
  if (tid == 0) wqs[row] = (m > 0.f) ? m / 127.f : 0.f;
}

// ---------------- v [b][g][t][d] -> vt [b][g][d][t] ----------------
__global__ __launch_bounds__(256) void vtrans_kernel(const ushort_t* __restrict__ v,
                                                     ushort_t* __restrict__ vt) {
  __shared__ ushort_t tile[64][72];
  const int bg = blockIdx.y;
  const int t0 = blockIdx.x * 64;
  const ushort_t* src = v + ((size_t)bg * TT + t0) * 64;
#pragma unroll
  for (int i = 0; i < 2; ++i) {
    int p = i * 256 + threadIdx.x;
    int r = p >> 3, c = (p & 7) * 8;
    *(short8*)&tile[r][c] = *(const short8*)(src + r * 64 + c);
  }
  __syncthreads();
  ushort_t* dst = vt + (size_t)bg * 64 * TT + t0;
#pragma unroll
  for (int i = 0; i < 2; ++i) {
    int p = i * 256 + threadIdx.x;
    int d = p >> 3, c = (p & 7) * 8;
    short8 o;
#pragma unroll
    for (int j = 0; j < 8; ++j) o[j] = tile[c + j][d];
    *(short8*)(dst + (size_t)d * TT + c) = o;
  }
}

// ---- i8 GEMM, BK=128, 128xBN tile, dbuf A+B, 2 blocks/CU ------------------
template <int MODE, int BN>
__global__ __launch_bounds__(512, 4) void gemmq_kernel(
    const s8* __restrict__ A, const s8* __restrict__ Bt,
    const float* __restrict__ sa, const float* __restrict__ sb,
    const float* __restrict__ cosT, const float* __restrict__ sinT,
    ushort_t* __restrict__ q_ws, ushort_t* __restrict__ k_ws,
    ushort_t* __restrict__ v_ws, float* __restrict__ kcache,
    float* __restrict__ vcache, float* __restrict__ outF) {
  constexpr int NT = 16;            // 2048 / 128
  constexpr int CW = BN / 4;        // cols per wave (48 | 32)
  constexpr int MF = 4;             // A-frags per wave (64 rows)
  constexpr int NF = CW / 16;       // B-frags per wave (3 | 2)
  constexpr int AGL = 2;
  constexpr int BGL = BN / 64;
  constexpr int GL = AGL + BGL;
  constexpr int ASZ = 128 * 128;
  constexpr int BSZ = BN * 128;
  __shared__ s8 sA[2 * ASZ];
  __shared__ s8 sB[2 * BSZ];
  const int tid = threadIdx.x;
  const int lane = tid & 63;
  const int w = tid >> 6;
  const int wm = w >> 2, wn = w & 3;
  const int bid = blockIdx.x;
  const int j = bid >> 3;
  const int by = 4 * (bid & 7) + (j & 3);
  const int bx = j >> 2;
  const int rowBase = by * 128;
  const int colBase = bx * BN;

  int aRO[AGL], aLO[AGL];
#pragma unroll
  for (int i = 0; i < AGL; ++i) {
    int c = i * 512 + tid;
    int r = c >> 3, lc = (c & 7) ^ (r & 7);
    aRO[i] = r * 2048 + lc * 16;
    aLO[i] = (i * 512 + (tid & ~63)) * 16;
  }
  int bRO[BGL], bLO[BGL];
#pragma unroll
  for (int i = 0; i < BGL; ++i) {
    int c = i * 512 + tid;
    int r = c >> 3, lc = (c & 7) ^ (r & 7);
    bRO[i] = r * 2048 + lc * 16;
    bLO[i] = (i * 512 + (tid & ~63)) * 16;
  }

  auto stage = [&](int bb, int kt) {
    const s8* ab = A + (size_t)rowBase * 2048 + kt * 128;
#pragma unroll
    for (int i = 0; i < AGL; ++i)
      gload_lds16(ab + aRO[i], &sA[bb * ASZ + aLO[i]]);
    const s8* bbp = Bt + (size_t)colBase * 2048 + kt * 128;
#pragma unroll
    for (int i = 0; i < BGL; ++i)
      gload_lds16(bbp + bRO[i], &sB[bb * BSZ + bLO[i]]);
  };

  int4v acc[MF][NF];
#pragma unroll
  for (int i = 0; i < MF; i++)
#pragma unroll
    for (int j2 = 0; j2 < NF; j2++) acc[i][j2] = int4v{0, 0, 0, 0};

  stage(0, 0);

  for (int k = 0; k < NT; ++k) {
    const int buf = k & 1;
    if (k + 1 < NT) {
      stage(buf ^ 1, k + 1);
      asm volatile("s_waitcnt vmcnt(%0)" :: "n"(GL) : "memory");
    } else {
      asm volatile("s_waitcnt vmcnt(0)" ::: "memory");
    }
    __builtin_amdgcn_s_barrier();

    const s8* Abuf = &sA[buf * ASZ];
    const s8* Bbuf = &sB[buf * BSZ];
#pragma unroll
    for (int ks = 0; ks < 2; ++ks) {
      int4v bfr[NF], af[MF];
#pragma unroll
      for (int ni = 0; ni < NF; ++ni) {
        int n = wn * CW + ni * 16 + (lane & 15);
        bfr[ni] = *(const int4v*)(&Bbuf[n * 128 +
            (((ks * 4 + (lane >> 4)) ^ (n & 7)) * 16)]);
      }
#pragma unroll
      for (int mi = 0; mi < MF; ++mi) {
        int r = wm * 64 + mi * 16 + (lane & 15);
        af[mi] = *(const int4v*)(&Abuf[r * 128 +
            (((ks * 4 + (lane >> 4)) ^ (r & 7)) * 16)]);
      }
      __builtin_amdgcn_s_setprio(1);
#pragma unroll
      for (int mi = 0; mi < MF; ++mi)
#pragma unroll
        for (int ni = 0; ni < NF; ++ni)
          acc[mi][ni] = __builtin_amdgcn_mfma_i32_16x16x64_i8(
              af[mi], bfr[ni], acc[mi][ni], 0, 0, 0);
      __builtin_amdgcn_s_setprio(0);
    }
    __builtin_amdgcn_s_barrier();
  }

  // ---- epilogue: dequant (acc * sa[row] * sb[col]) ----
#pragma unroll
  for (int mi = 0; mi < MF; ++mi) {
    int rg0 = rowBase + wm * 64 + mi * 16 + ((lane >> 4) * 4);
    float sar[4];
#pragma unroll
    for (int jj = 0; jj < 4; ++jj) sar[jj] = sa[rg0 + jj];
#pragma unroll
    for (int ni = 0; ni < NF; ++ni) {
      int cg = colBase + wn * CW + ni * 16 + (lane & 15);
      const float sbc = sb[cg];
      int4v v4 = acc[mi][ni];
#pragma unroll
      for (int j2 = 0; j2 < 4; ++j2) {
        float v = (float)v4[j2] * sar[j2] * sbc;
        int row = rg0 + j2;
        if constexpr (MODE == 0) {
          float pv = __shfl_xor(v, 1);
          int bb2 = row >> 11, tq = row & (TT - 1);
          int d = cg & 63, i2 = d >> 1;
          if (cg < 2048) {  // q (scale folds 1/8 and log2(e) for exp2 softmax)
            float cc = cosT[tq * 32 + i2], ss = sinT[tq * 32 + i2];
            float out = (d & 1) ? (pv * ss + v * cc) : (v * cc - pv * ss);
            int hh = cg >> 6;
            q_ws[(((size_t)(bb2 * NH + hh)) * TT + tq) * 64 + d] = f2bf(out * 0.18033688f);
          } else if (cg < 2560) {  // k (roped)
            float cc = cosT[tq * 32 + i2], ss = sinT[tq * 32 + i2];
            float out = (d & 1) ? (pv * ss + v * cc) : (v * cc - pv * ss);
            int gg = (cg - 2048) >> 6;
            kcache[(((size_t)(bb2 * TT + tq)) * NG + gg) * 64 + d] = out;
            k_ws[(((size_t)(bb2 * NG + gg)) * TT + tq) * 64 + d] = f2bf(out);
          } else {  // v (row-major; vtrans builds vt)
            int gg = (cg - 2560) >> 6;
            vcache[(((size_t)(bb2 * TT + tq)) * NG + gg) * 64 + d] = v;
            v_ws[(((size_t)(bb2 * NG + gg)) * TT + tq) * 64 + d] = f2bf(v);
          }
        } else {
          outF[(size_t)row * 2048 + cg] = v;
        }
      }
    }
  }
}

// ---------------- flash attention, KVBLK=128: swapped 32x32 MFMA -----------
// 2 blocks/CU (64 KB LDS); LPT order qt=15-(bid>>6) with dynamic refill.
// K tile [128 keys][64 d]: 8-chunk XOR swizzle, row stride 64 ushorts.
// VT tile [64 d][128 keys]: 16-chunk XOR swizzle, row stride 128 ushorts
// (chunk = 8 ushorts = 16 B; read addr = row*128 + (ch^(row&15))*8).
#define PACK(SV, E, OUT)                                        \
  {                                                             \
    uint32_t A0 = cvtpk(SV[8 * E + 0], SV[8 * E + 1]);          \
    uint32_t A1 = cvtpk(SV[8 * E + 2], SV[8 * E + 3]);          \
    uint32_t B0 = cvtpk(SV[8 * E + 4], SV[8 * E + 5]);          \
    uint32_t B1 = cvtpk(SV[8 * E + 6], SV[8 * E + 7]);          \
    asm("v_permlane32_swap_b32 %0, %1" : "+v"(A0), "+v"(B0));   \
    asm("v_permlane32_swap_b32 %0, %1" : "+v"(A1), "+v"(B1));   \
    union { uint32_t u[4]; short8 s8v; } UU;                    \
    UU.u[0] = A0; UU.u[1] = A1; UU.u[2] = B0; UU.u[3] = B1;     \
    OUT = UU.s8v;                                               \
  }

__global__ __launch_bounds__(256, 2) void attn_kernel(const ushort_t* __restrict__ qw,
                                                      const ushort_t* __restrict__ kw,
                                                      const ushort_t* __restrict__ vtw,
                                                      ushort_t* __restrict__ attn) {
  __shared__ ushort_t sK[2][8192];    // [128 keys][64 d]
  __shared__ ushort_t sVT[2][8192];   // [64 d][128 keys]
  const int tid = threadIdx.x;
  const int lane = tid & 63;
  const int w = tid >> 6;
  const int hi = lane >> 5;
  const int col = lane & 31;
  const int bid = blockIdx.x;
  const int pair = 2 * (bid & 7) + ((bid >> 3) & 1);
  const int rep = (bid >> 4) & 3;
  const int qt = 15 - (bid >> 6);            // LPT: heavy first
  const int b = pair >> 3, g = pair & 7;
  const int h = g * 4 + rep;
  const int q0w = qt * 128 + w * 32;
  const int qg = q0w + col;
  const int ntiles = qt + 1;                 // 128-key tiles

  const ushort_t* qbase = qw + ((size_t)(b * NH + h) * TT + qg) * 64;
  const ushort_t* kbase = kw + (size_t)(b * NG + g) * TT * 64;
  const ushort_t* vtbase = vtw + (size_t)(b * NG + g) * 64 * TT;

  short8 qf[4];
#pragma unroll
  for (int dsub = 0; dsub < 4; ++dsub)
    qf[dsub] = *(const short8*)(qbase + dsub * 16 + hi * 8);

  // staging maps: K tile = 1024 chunks (128 rows x 8); VT = 1024 (64 rows x 16)
  int kRO[4], vRO[4], sOF[4];
#pragma unroll
  for (int i = 0; i < 4; ++i) {
    int c = i * 256 + tid;
    int kr = c >> 3, kc = (c & 7) ^ (kr & 7);
    kRO[i] = kr * 64 + kc * 8;
    int vr = c >> 4, vc = (c & 15) ^ (vr & 15);
    vRO[i] = vr * 2048 + vc * 8;
    sOF[i] = (i * 256 + (tid & ~63)) * 8;
  }

  auto stage = [&](int bb, int k0) {
#pragma unroll
    for (int i = 0; i < 4; ++i)
      gload_lds16(kbase + (size_t)k0 * 64 + kRO[i], &sK[bb][sOF[i]]);
#pragma unroll
    for (int i = 0; i < 4; ++i)
      gload_lds16(vtbase + k0 + vRO[i], &sVT[bb][sOF[i]]);
  };

  f32x16 o0 = {};
  f32x16 o1 = {};
  f32x16 l16 = {};
  float m_run = -3.0e38f;

  stage(0, 0);
  asm volatile("s_waitcnt vmcnt(0)" ::: "memory");
  __syncthreads();

  for (int kt = 0; kt < ntiles; ++kt) {
    const int k0 = kt * 128;
    const int buf = kt & 1;
    if (kt + 1 < ntiles) stage(buf ^ 1, k0 + 128);
    const ushort_t* K = sK[buf];
    const ushort_t* V = sVT[buf];
    f32x16 s0 = {}, s1 = {}, s2 = {}, s3 = {};
    __builtin_amdgcn_s_setprio(1);
#pragma unroll
    for (int dsub = 0; dsub < 4; ++dsub) {
      const int ch = dsub * 2 + hi;
#pragma unroll
      for (int kb = 0; kb < 4; ++kb) {
        int kr = kb * 32 + col;
        short8 a = *(const short8*)(K + kr * 64 + ((ch ^ (kr & 7)) * 8));
        if (kb == 0) s0 = __builtin_amdgcn_mfma_f32_32x32x16_bf16(a, qf[dsub], s0, 0, 0, 0);
        if (kb == 1) s1 = __builtin_amdgcn_mfma_f32_32x32x16_bf16(a, qf[dsub], s1, 0, 0, 0);
        if (kb == 2) s2 = __builtin_amdgcn_mfma_f32_32x32x16_bf16(a, qf[dsub], s2, 0, 0, 0);
        if (kb == 3) s3 = __builtin_amdgcn_mfma_f32_32x32x16_bf16(a, qf[dsub], s3, 0, 0, 0);
      }
    }
    __builtin_amdgcn_s_setprio(0);
    if (kt == ntiles - 1) {   // diagonal: causal mask (only last tile)
#pragma unroll
      for (int r = 0; r < 16; ++r) {
        int key5 = (r & 3) + 8 * (r >> 2) + 4 * hi;
        if (k0 + key5 > qg) s0[r] = -3.0e38f;
        if (k0 + 32 + key5 > qg) s1[r] = -3.0e38f;
        if (k0 + 64 + key5 > qg) s2[r] = -3.0e38f;
        if (k0 + 96 + key5 > qg) s3[r] = -3.0e38f;
      }
    }
    // tile max over 64 values
    float tm[16];
#pragma unroll
    for (int r = 0; r < 16; ++r)
      tm[r] = max3f(fmaxf(s0[r], s1[r]), s2[r], s3[r]);
    float p0 = max3f(tm[0], tm[1], tm[2]);
    float p1 = max3f(tm[3], tm[4], tm[5]);
    float p2 = max3f(tm[6], tm[7], tm[8]);
    float p3 = max3f(tm[9], tm[10], tm[11]);
    float p4 = max3f(tm[12], tm[13], tm[14]);
    float mtl = max3f(max3f(p0, p1, p2), max3f(p3, p4, tm[15]), -3.0e38f);
    float mt = fmaxf(mtl, __shfl_xor(mtl, 32));
    if (!__all(mt - m_run <= 8.0f)) {
      float mn = fmaxf(m_run, mt);
      float al = exp2fast(m_run - mn);
      m_run = mn;
#pragma unroll
      for (int r = 0; r < 16; ++r) { o0[r] *= al; o1[r] *= al; l16[r] *= al; }
    }
#pragma unroll
    for (int r = 0; r < 16; ++r) {
      s0[r] = exp2fast(s0[r] - m_run);
      s1[r] = exp2fast(s1[r] - m_run);
      s2[r] = exp2fast(s2[r] - m_run);
      s3[r] = exp2fast(s3[r] - m_run);
      l16[r] += (s0[r] + s1[r]) + (s2[r] + s3[r]);
    }
    short8 pb;
#define PVMM(KS)                                                            \
  {                                                                         \
    const int ch = KS * 2 + hi;                                             \
    short8 va = *(const short8*)(V + col * 128 + ((ch ^ (col & 15)) * 8));  \
    short8 vb = *(const short8*)(V + (32 + col) * 128 +                     \
                                 ((ch ^ ((32 + col) & 15)) * 8));           \
    __builtin_amdgcn_s_setprio(1);                                          \
    o0 = __builtin_amdgcn_mfma_f32_32x32x16_bf16(va, pb, o0, 0, 0, 0);      \
    o1 = __builtin_amdgcn_mfma_f32_32x32x16_bf16(vb, pb, o1, 0, 0, 0);      \
    __builtin_amdgcn_s_setprio(0);                                          \
  }
    PACK(s0, 0, pb); PVMM(0)
    PACK(s0, 1, pb); PVMM(1)
    PACK(s1, 0, pb); PVMM(2)
    PACK(s1, 1, pb); PVMM(3)
    PACK(s2, 0, pb); PVMM(4)
    PACK(s2, 1, pb); PVMM(5)
    PACK(s3, 0, pb); PVMM(6)
    PACK(s3, 1, pb); PVMM(7)
#undef PVMM
    asm volatile("s_waitcnt vmcnt(0)" ::: "memory");
    __syncthreads();
  }

  // deferred l reduction
  float l4[4];
#pragma unroll
  for (int r = 0; r < 4; ++r)
    l4[r] = (l16[4 * r] + l16[4 * r + 1]) + (l16[4 * r + 2] + l16[4 * r + 3]);
  float lsum = (l4[0] + l4[1]) + (l4[2] + l4[3]);
  float l_run = lsum + __shfl_xor(lsum, 32);
  const float inv = 1.f / l_run;
  ushort_t* obase = attn + ((size_t)b * TT + qg) * 2048 + h * 64;
#pragma unroll
  for (int g4 = 0; g4 < 4; ++g4) {
    int d = g4 * 8 + hi * 4;
    uint2v u2v;
    u2v[0] = cvtpk(o0[4 * g4 + 0] * inv, o0[4 * g4 + 1] * inv);
    u2v[1] = cvtpk(o0[4 * g4 + 2] * inv, o0[4 * g4 + 3] * inv);
    *(uint2v*)(obase + d) = u2v;
    uint2v u2b;
    u2b[0] = cvtpk(o1[4 * g4 + 0] * inv, o1[4 * g4 + 1] * inv);
    u2b[1] = cvtpk(o1[4 * g4 + 2] * inv, o1[4 * g4 + 3] * inv);
    *(uint2v*)(obase + 32 + d) = u2b;
  }
}

extern "C" void kernel_launch(void* const* d_in, const int* in_sizes, int n_in,
                              void* d_out, int out_size, void* d_ws, size_t ws_size,
                              hipStream_t stream) {
  (void)in_sizes; (void)n_in; (void)out_size; (void)ws_size;
  const float* x    = (const float*)d_in[0];
  const float* cosT = (const float*)d_in[1];
  const float* sinT = (const float*)d_in[2];
  const float* Wq   = (const float*)d_in[4];
  const float* Wk   = (const float*)d_in[5];
  const float* Wv   = (const float*)d_in[6];
  const float* Wo   = (const float*)d_in[7];

  float* outF   = (float*)d_out;
  float* kcache = outF + (size_t)8388608;             // B*T*C
  float* vcache = kcache + (size_t)2097152;           // B*T*G*D

  uint8_t* ws = (uint8_t*)d_ws;
  s8*       xq     = (s8*)(ws);
  float*    xs     = (float*)(ws + 8388608);
  float*    wqs    = (float*)(ws + 8388608 + 65536);
  float*    wos    = (float*)(ws + 8388608 + 131072);
  float*    as_s   = (float*)(ws + 8388608 + 196608);
  ushort_t* vt_ws  = (ushort_t*)(ws + 9437184);
  ushort_t* wqkvT  = (ushort_t*)(ws + 16777216);
  ushort_t* attn_ws= (ushort_t*)(ws + 16777216);
  s8*       wq_q   = (s8*)(ws + 35651584);
  ushort_t* q_ws   = (ushort_t*)(ws + 41943040);
  s8*       aq     = (s8*)(ws + 41943040);
  ushort_t* k_ws   = (ushort_t*)(ws + 58720256);
  ushort_t* v_ws   = (ushort_t*)(ws + 62914560);
  ushort_t* woT    = (ushort_t*)(ws + 67108864);
  s8*       wo_q   = (s8*)(ws + 75497472);

  prep1_kernel<<<14336, 256, 0, stream>>>(x, xq, xs, Wq, Wk, Wv, Wo, wqkvT, woT);
  wqall_kernel<<<5120, 256, 0, stream>>>(wqkvT, woT, wq_q, wo_q, wqs, wos);

  gemmq_kernel<0, 192><<<512, 512, 0, stream>>>(xq, wq_q, xs, wqs, cosT, sinT,
                                                q_ws, k_ws, v_ws, kcache, vcache,
                                                nullptr);
  vtrans_kernel<<<dim3(32, 16), 256, 0, stream>>>(v_ws, vt_ws);
  attn_kernel<<<1024, 256, 0, stream>>>(q_ws, k_ws, vt_ws, attn_ws);
  wq_kernel<<<4096, 256, 0, stream>>>(attn_ws, aq, as_s);
  gemmq_kernel<1, 128><<<512, 512, 0, stream>>>(aq, wo_q, as_s, wos, nullptr, nullptr,
                                                nullptr, nullptr, nullptr, nullptr,
                                                nullptr, outF);
}

// Round 20
// 154.561 us; speedup vs baseline: 1.0311x; 1.0311x over previous
//
#include <hip/hip_runtime.h>
#include <cstdint>
#include <cstddef>

typedef unsigned short ushort_t;
typedef signed char s8;
typedef __attribute__((ext_vector_type(4))) float f32x4;
typedef __attribute__((ext_vector_type(16))) float f32x16;
typedef __attribute__((ext_vector_type(8))) short short8;
typedef __attribute__((ext_vector_type(4))) float float4_t;
typedef __attribute__((ext_vector_type(4))) unsigned short ushort4_t;
typedef __attribute__((ext_vector_type(2))) unsigned int uint2v;
typedef __attribute__((ext_vector_type(4))) int int4v;
typedef __attribute__((ext_vector_type(2))) int int2v;

#define KD 2048     // inner dim of both GEMMs
#define TT 2048     // sequence length T
#define NH 32       // heads
#define NG 8        // kv groups

__device__ __forceinline__ ushort_t f2bf(float f) {
  union { float f; uint32_t u; } cv; cv.f = f;
  uint32_t u = cv.u;
  return (ushort_t)((u + 0x7FFFu + ((u >> 16) & 1u)) >> 16);
}

__device__ __forceinline__ float bf2f(ushort_t v) {
  union { uint32_t u; float f; } cv; cv.u = ((uint32_t)v) << 16;
  return cv.f;
}

__device__ __forceinline__ uint32_t cvtpk(float a, float b) {
  uint32_t r;
  asm("v_cvt_pk_bf16_f32 %0, %1, %2" : "=v"(r) : "v"(a), "v"(b));
  return r;
}

__device__ __forceinline__ float exp2fast(float x) {
  float r;
  asm("v_exp_f32 %0, %1" : "=v"(r) : "v"(x));
  return r;
}

__device__ __forceinline__ float max3f(float a, float b, float c) {
  return fmaxf(fmaxf(a, b), c);   // clang fuses to v_max3_f32
}

__device__ __forceinline__ void gload_lds16(const void* g, void* l) {
  __builtin_amdgcn_global_load_lds(
      (const __attribute__((address_space(1))) unsigned int*)g,
      (__attribute__((address_space(3))) unsigned int*)l, 16, 0, 0);
}

// ---- prep1: xq (bid<4096) + weight f32->bf16 transpose (bid>=4096) --------
__global__ __launch_bounds__(256) void prep1_kernel(const float* __restrict__ x,
                                                    s8* __restrict__ xq,
                                                    float* __restrict__ xs,
                                                    const float* __restrict__ Wq,
                                                    const float* __restrict__ Wk,
                                                    const float* __restrict__ Wv,
                                                    const float* __restrict__ Wo,
                                                    ushort_t* __restrict__ wqkvT,
                                                    ushort_t* __restrict__ woT) {
  const int tid = threadIdx.x;
  if (blockIdx.x < 4096) {
    const int row = blockIdx.x;
    const float* src = x + (size_t)row * 2048 + tid * 8;
    float4_t a = *(const float4_t*)(src);
    float4_t b = *(const float4_t*)(src + 4);
    float m = fmaxf(fmaxf(fmaxf(fabsf(a[0]), fabsf(a[1])), fmaxf(fabsf(a[2]), fabsf(a[3]))),
                    fmaxf(fmaxf(fabsf(b[0]), fabsf(b[1])), fmaxf(fabsf(b[2]), fabsf(b[3]))));
#pragma unroll
    for (int st = 32; st > 0; st >>= 1) m = fmaxf(m, __shfl_xor(m, st));
    __shared__ float red[4];
    if ((tid & 63) == 0) red[tid >> 6] = m;
    __syncthreads();
    m = fmaxf(fmaxf(red[0], red[1]), fmaxf(red[2], red[3]));
    const float inv = (m > 0.f) ? 127.f / m : 0.f;
    union { s8 c[8]; int2v v; } pk;
#pragma unroll
    for (int i = 0; i < 4; ++i) {
      pk.c[i]     = (s8)__float2int_rn(a[i] * inv);
      pk.c[4 + i] = (s8)__float2int_rn(b[i] * inv);
    }
    *(int2v*)(xq + (size_t)row * 2048 + tid * 8) = pk.v;
    if (tid == 0) xs[row] = (m > 0.f) ? m / 127.f : 0.f;
    return;
  }
  // weight transpose part
  __shared__ float tile[32][33];
  const int bid = blockIdx.x - 4096;
  const float* src;
  ushort_t* dst;
  int Nc, bx, by;
  if (bid < 4096)      { src = Wq; dst = wqkvT;                       Nc = 2048; int r = bid;        bx = r & 63; by = r >> 6; }
  else if (bid < 5120) { src = Wk; dst = wqkvT + (size_t)2048 * KD;   Nc = 512;  int r = bid - 4096; bx = r & 15; by = r >> 4; }
  else if (bid < 6144) { src = Wv; dst = wqkvT + (size_t)2560 * KD;   Nc = 512;  int r = bid - 5120; bx = r & 15; by = r >> 4; }
  else                 { src = Wo; dst = woT;                         Nc = 2048; int r = bid - 6144; bx = r & 63; by = r >> 6; }
  const int tx = tid & 31, ty = tid >> 5;
  const int c0 = bx * 32, r0 = by * 32;
#pragma unroll
  for (int i = 0; i < 4; i++)
    tile[ty + i * 8][tx] = src[(size_t)(r0 + ty + i * 8) * Nc + c0 + tx];
  __syncthreads();
#pragma unroll
  for (int i = 0; i < 4; i++)
    dst[(size_t)(c0 + ty + i * 8) * KD + r0 + tx] = f2bf(tile[tx][ty + i * 8]);
}

// ------- wqall: both weight-quant passes, one launch -----------------------
__global__ __launch_bounds__(256) void wqall_kernel(const ushort_t* __restrict__ wqkvT,
                                                    const ushort_t* __restrict__ woT,
                                                    s8* __restrict__ wq_q,
                                                    s8* __restrict__ wo_q,
                                                    float* __restrict__ wqs,
                                                    float* __restrict__ wos) {
  const int bid = blockIdx.x;
  const ushort_t* wt;
  s8* wq;
  float* sc;
  int row;
  if (bid < 3072) { wt = wqkvT; wq = wq_q; sc = wqs; row = bid; }
  else            { wt = woT;   wq = wo_q; sc = wos; row = bid - 3072; }
  const int tid = threadIdx.x;
  short8 v8 = *(const short8*)(wt + (size_t)row * 2048 + tid * 8);
  float f[8];
#pragma unroll
  for (int i = 0; i < 8; ++i) f[i] = bf2f((ushort_t)v8[i]);
  float m = 0.f;
#pragma unroll
  for (int i = 0; i < 8; ++i) m = fmaxf(m, fabsf(f[i]));
#pragma unroll
  for (int st = 32; st > 0; st >>= 1) m = fmaxf(m, __shfl_xor(m, st));
  __shared__ float red[4];
  if ((tid & 63) == 0) red[tid >> 6] = m;
  __syncthreads();
  m = fmaxf(fmaxf(red[0], red[1]), fmaxf(red[2], red[3]));
  const float inv = (m > 0.f) ? 127.f / m : 0.f;
  union { s8 c[8]; int2v v; } pk;
#pragma unroll
  for (int i = 0; i < 8; ++i) pk.c[i] = (s8)__float2int_rn(f[i] * inv);
  *(int2v*)(wq + (size_t)row * 2048 + tid * 8) = pk.v;
  if (tid == 0) sc[row] = (m > 0.f) ? m / 127.f : 0.f;
}

// ------- generic bf16 [rows][2048] -> i8 per-row-scaled (attn out) ---------
__global__ __launch_bounds__(256) void wq_kernel(const ushort_t* __restrict__ wt,
                                                 s8* __restrict__ wq,
                                                 float* __restrict__ wqs) {
  const int row = blockIdx.x;
  const int tid = threadIdx.x;
  short8 v8 = *(const short8*)(wt + (size_t)row * 2048 + tid * 8);
  float f[8];
#pragma unroll
  for (int i = 0; i < 8; ++i) f[i] = bf2f((ushort_t)v8[i]);
  float m = 0.f;
#pragma unroll
  for (int i = 0; i < 8; ++i) m = fmaxf(m, fabsf(f[i]));
#pragma unroll
  for (int st = 32; st > 0; st >>= 1) m = fmaxf(m, __shfl_xor(m, st));
  __shared__ float red[4];
  if ((tid & 63) == 0) red[tid >> 6] = m;
  __syncthreads();
  m = fmaxf(fmaxf(red[0], red[1]), fmaxf(red[2], red[3]));
  const float inv = (m > 0.f) ? 127.f / m : 0.f;
  union { s8 c[8]; int2v v; } pk;
#pragma unroll
  for (int i = 0; i < 8; ++i) pk.c[i] = (s8)__float2int_rn(f[i] * inv);
  *(int2v*)(wq + (size_t)row * 2048 + tid * 8) = pk.v;
  if (tid == 0) wqs[row] = (m > 0.f) ? m / 127.f : 0.f;
}

// ---------------- v [b][g][t][d] -> vt [b][g][d][t] ----------------
__global__ __launch_bounds__(256) void vtrans_kernel(const ushort_t* __restrict__ v,
                                                     ushort_t* __restrict__ vt) {
  __shared__ ushort_t tile[64][72];
  const int bg = blockIdx.y;
  const int t0 = blockIdx.x * 64;
  const ushort_t* src = v + ((size_t)bg * TT + t0) * 64;
#pragma unroll
  for (int i = 0; i < 2; ++i) {
    int p = i * 256 + threadIdx.x;
    int r = p >> 3, c = (p & 7) * 8;
    *(short8*)&tile[r][c] = *(const short8*)(src + r * 64 + c);
  }
  __syncthreads();
  ushort_t* dst = vt + (size_t)bg * 64 * TT + t0;
#pragma unroll
  for (int i = 0; i < 2; ++i) {
    int p = i * 256 + threadIdx.x;
    int d = p >> 3, c = (p & 7) * 8;
    short8 o;
#pragma unroll
    for (int j = 0; j < 8; ++j) o[j] = tile[c + j][d];
    *(short8*)(dst + (size_t)d * TT + c) = o;
  }
}

// ---- i8 GEMM, BK=128, 128xBN tile, dbuf A+B, 2 blocks/CU ------------------
template <int MODE, int BN>
__global__ __launch_bounds__(512, 4) void gemmq_kernel(
    const s8* __restrict__ A, const s8* __restrict__ Bt,
    const float* __restrict__ sa, const float* __restrict__ sb,
    const float* __restrict__ cosT, const float* __restrict__ sinT,
    ushort_t* __restrict__ q_ws, ushort_t* __restrict__ k_ws,
    ushort_t* __restrict__ v_ws, float* __restrict__ kcache,
    float* __restrict__ vcache, float* __restrict__ outF) {
  constexpr int NT = 16;            // 2048 / 128
  constexpr int CW = BN / 4;        // cols per wave (48 | 32)
  constexpr int MF = 4;             // A-frags per wave (64 rows)
  constexpr int NF = CW / 16;       // B-frags per wave (3 | 2)
  constexpr int AGL = 2;
  constexpr int BGL = BN / 64;
  constexpr int GL = AGL + BGL;
  constexpr int ASZ = 128 * 128;
  constexpr int BSZ = BN * 128;
  __shared__ s8 sA[2 * ASZ];
  __shared__ s8 sB[2 * BSZ];
  const int tid = threadIdx.x;
  const int lane = tid & 63;
  const int w = tid >> 6;
  const int wm = w >> 2, wn = w & 3;
  const int bid = blockIdx.x;
  const int j = bid >> 3;
  const int by = 4 * (bid & 7) + (j & 3);
  const int bx = j >> 2;
  const int rowBase = by * 128;
  const int colBase = bx * BN;

  int aRO[AGL], aLO[AGL];
#pragma unroll
  for (int i = 0; i < AGL; ++i) {
    int c = i * 512 + tid;
    int r = c >> 3, lc = (c & 7) ^ (r & 7);
    aRO[i] = r * 2048 + lc * 16;
    aLO[i] = (i * 512 + (tid & ~63)) * 16;
  }
  int bRO[BGL], bLO[BGL];
#pragma unroll
  for (int i = 0; i < BGL; ++i) {
    int c = i * 512 + tid;
    int r = c >> 3, lc = (c & 7) ^ (r & 7);
    bRO[i] = r * 2048 + lc * 16;
    bLO[i] = (i * 512 + (tid & ~63)) * 16;
  }

  auto stage = [&](int bb, int kt) {
    const s8* ab = A + (size_t)rowBase * 2048 + kt * 128;
#pragma unroll
    for (int i = 0; i < AGL; ++i)
      gload_lds16(ab + aRO[i], &sA[bb * ASZ + aLO[i]]);
    const s8* bbp = Bt + (size_t)colBase * 2048 + kt * 128;
#pragma unroll
    for (int i = 0; i < BGL; ++i)
      gload_lds16(bbp + bRO[i], &sB[bb * BSZ + bLO[i]]);
  };

  int4v acc[MF][NF];
#pragma unroll
  for (int i = 0; i < MF; i++)
#pragma unroll
    for (int j2 = 0; j2 < NF; j2++) acc[i][j2] = int4v{0, 0, 0, 0};

  stage(0, 0);

  for (int k = 0; k < NT; ++k) {
    const int buf = k & 1;
    if (k + 1 < NT) {
      stage(buf ^ 1, k + 1);
      asm volatile("s_waitcnt vmcnt(%0)" :: "n"(GL) : "memory");
    } else {
      asm volatile("s_waitcnt vmcnt(0)" ::: "memory");
    }
    __builtin_amdgcn_s_barrier();

    const s8* Abuf = &sA[buf * ASZ];
    const s8* Bbuf = &sB[buf * BSZ];
#pragma unroll
    for (int ks = 0; ks < 2; ++ks) {
      int4v bfr[NF], af[MF];
#pragma unroll
      for (int ni = 0; ni < NF; ++ni) {
        int n = wn * CW + ni * 16 + (lane & 15);
        bfr[ni] = *(const int4v*)(&Bbuf[n * 128 +
            (((ks * 4 + (lane >> 4)) ^ (n & 7)) * 16)]);
      }
#pragma unroll
      for (int mi = 0; mi < MF; ++mi) {
        int r = wm * 64 + mi * 16 + (lane & 15);
        af[mi] = *(const int4v*)(&Abuf[r * 128 +
            (((ks * 4 + (lane >> 4)) ^ (r & 7)) * 16)]);
      }
      __builtin_amdgcn_s_setprio(1);
#pragma unroll
      for (int mi = 0; mi < MF; ++mi)
#pragma unroll
        for (int ni = 0; ni < NF; ++ni)
          acc[mi][ni] = __builtin_amdgcn_mfma_i32_16x16x64_i8(
              af[mi], bfr[ni], acc[mi][ni], 0, 0, 0);
      __builtin_amdgcn_s_setprio(0);
    }
    __builtin_amdgcn_s_barrier();
  }

  // ---- epilogue: dequant (acc * sa[row] * sb[col]) ----
#pragma unroll
  for (int mi = 0; mi < MF; ++mi) {
    int rg0 = rowBase + wm * 64 + mi * 16 + ((lane >> 4) * 4);
    float sar[4];
#pragma unroll
    for (int jj = 0; jj < 4; ++jj) sar[jj] = sa[rg0 + jj];
#pragma unroll
    for (int ni = 0; ni < NF; ++ni) {
      int cg = colBase + wn * CW + ni * 16 + (lane & 15);
      const float sbc = sb[cg];
      int4v v4 = acc[mi][ni];
#pragma unroll
      for (int j2 = 0; j2 < 4; ++j2) {
        float v = (float)v4[j2] * sar[j2] * sbc;
        int row = rg0 + j2;
        if constexpr (MODE == 0) {
          float pv = __shfl_xor(v, 1);
          int bb2 = row >> 11, tq = row & (TT - 1);
          int d = cg & 63, i2 = d >> 1;
          if (cg < 2048) {  // q (scale folds 1/8 and log2(e) for exp2 softmax)
            float cc = cosT[tq * 32 + i2], ss = sinT[tq * 32 + i2];
            float out = (d & 1) ? (pv * ss + v * cc) : (v * cc - pv * ss);
            int hh = cg >> 6;
            q_ws[(((size_t)(bb2 * NH + hh)) * TT + tq) * 64 + d] = f2bf(out * 0.18033688f);
          } else if (cg < 2560) {  // k (roped)
            float cc = cosT[tq * 32 + i2], ss = sinT[tq * 32 + i2];
            float out = (d & 1) ? (pv * ss + v * cc) : (v * cc - pv * ss);
            int gg = (cg - 2048) >> 6;
            kcache[(((size_t)(bb2 * TT + tq)) * NG + gg) * 64 + d] = out;
            k_ws[(((size_t)(bb2 * NG + gg)) * TT + tq) * 64 + d] = f2bf(out);
          } else {  // v (row-major; vtrans builds vt)
            int gg = (cg - 2560) >> 6;
            vcache[(((size_t)(bb2 * TT + tq)) * NG + gg) * 64 + d] = v;
            v_ws[(((size_t)(bb2 * NG + gg)) * TT + tq) * 64 + d] = f2bf(v);
          }
        } else {
          outF[(size_t)row * 2048 + cg] = v;
        }
      }
    }
  }
}

// ---------------- flash attention (R17 config): KVBLK=64, 4 blocks/CU ------
// Per-CU balance (confirmed R15/R16): co-resident blocks = {c,c+256,c+512,c+768};
// qt Latin table over (bits6-7, bits8-9) -> exactly 68 KV-tiles per CU.
// Deferred l-sum, max3 tile-max, setprio on MFMA clusters.
#define PACK(SV, E, OUT)                                        \
  {                                                             \
    uint32_t A0 = cvtpk(SV[8 * E + 0], SV[8 * E + 1]);          \
    uint32_t A1 = cvtpk(SV[8 * E + 2], SV[8 * E + 3]);          \
    uint32_t B0 = cvtpk(SV[8 * E + 4], SV[8 * E + 5]);          \
    uint32_t B1 = cvtpk(SV[8 * E + 6], SV[8 * E + 7]);          \
    asm("v_permlane32_swap_b32 %0, %1" : "+v"(A0), "+v"(B0));   \
    asm("v_permlane32_swap_b32 %0, %1" : "+v"(A1), "+v"(B1));   \
    union { uint32_t u[4]; short8 s8v; } UU;                    \
    UU.u[0] = A0; UU.u[1] = A1; UU.u[2] = B0; UU.u[3] = B1;     \
    OUT = UU.s8v;                                               \
  }

__global__ __launch_bounds__(256, 4) void attn_kernel(const ushort_t* __restrict__ qw,
                                                      const ushort_t* __restrict__ kw,
                                                      const ushort_t* __restrict__ vtw,
                                                      ushort_t* __restrict__ attn) {
  __shared__ ushort_t sK[2][4096];
  __shared__ ushort_t sVT[2][4096];
  const int tid = threadIdx.x;
  const int lane = tid & 63;
  const int w = tid >> 6;
  const int hi = lane >> 5;
  const int col = lane & 31;
  const int bid = blockIdx.x;
  const int xcd = bid & 7;
  const int b3 = (bid >> 3) & 1;
  const int rep = (bid >> 4) & 3;
  const int w2 = (bid >> 6) & 3;
  const int u = (bid >> 8) & 3;
  const int qt = (u & 1) ? (2 * w2 + (u >> 1)) : (15 - 2 * w2 - (u >> 1));
  const int pair = 2 * xcd + b3;
  const int b = pair >> 3, g = pair & 7;
  const int h = g * 4 + rep;
  const int q0w = qt * 128 + w * 32;
  const int qg = q0w + col;
  const int ntiles = 2 * qt + 2;

  const ushort_t* qbase = qw + ((size_t)(b * NH + h) * TT + qg) * 64;
  const ushort_t* kbase = kw + (size_t)(b * NG + g) * TT * 64;
  const ushort_t* vtbase = vtw + (size_t)(b * NG + g) * 64 * TT;

  short8 qf[4];
#pragma unroll
  for (int dsub = 0; dsub < 4; ++dsub)
    qf[dsub] = *(const short8*)(qbase + dsub * 16 + hi * 8);

  const int r0 = tid >> 3;
  const int cl = (tid & 7) ^ (r0 & 7);
  const ushort_t* kS0 = kbase + r0 * 64 + cl * 8;
  const ushort_t* kS1 = kbase + (r0 + 32) * 64 + cl * 8;
  const ushort_t* vS0 = vtbase + (size_t)r0 * TT + cl * 8;
  const ushort_t* vS1 = vtbase + (size_t)(r0 + 32) * TT + cl * 8;
  const int off0 = (tid & ~63) * 8;
  const int off1 = off0 + 2048;

  auto stage = [&](int bb, int k0) {
    gload_lds16(kS0 + (size_t)k0 * 64, &sK[bb][off0]);
    gload_lds16(kS1 + (size_t)k0 * 64, &sK[bb][off1]);
    gload_lds16(vS0 + k0, &sVT[bb][off0]);
    gload_lds16(vS1 + k0, &sVT[bb][off1]);
  };

  f32x16 o0 = {};
  f32x16 o1 = {};
  f32x16 l16 = {};
  float m_run = -3.0e38f;

  stage(0, 0);
  asm volatile("s_waitcnt vmcnt(0)" ::: "memory");
  __syncthreads();

  for (int kt = 0; kt < ntiles; ++kt) {
    const int k0 = kt * 64;
    const int buf = kt & 1;
    if (kt + 1 < ntiles) stage(buf ^ 1, k0 + 64);
    if (k0 <= q0w + 31) {
      const ushort_t* K = sK[buf];
      const ushort_t* V = sVT[buf];
      f32x16 s0 = {};
      f32x16 s1 = {};
      __builtin_amdgcn_s_setprio(1);
#pragma unroll
      for (int dsub = 0; dsub < 4; ++dsub) {
        const int ch = dsub * 2 + hi;
        const int sw = ((ch ^ (col & 7)) * 8);
        short8 a0 = *(const short8*)(K + col * 64 + sw);
        short8 a1 = *(const short8*)(K + (32 + col) * 64 + sw);
        s0 = __builtin_amdgcn_mfma_f32_32x32x16_bf16(a0, qf[dsub], s0, 0, 0, 0);
        s1 = __builtin_amdgcn_mfma_f32_32x32x16_bf16(a1, qf[dsub], s1, 0, 0, 0);
      }
      __builtin_amdgcn_s_setprio(0);
      if (k0 + 63 > q0w) {
#pragma unroll
        for (int r = 0; r < 16; ++r) {
          int key5 = (r & 3) + 8 * (r >> 2) + 4 * hi;
          if (k0 + key5 > qg) s0[r] = -3.0e38f;
          if (k0 + 32 + key5 > qg) s1[r] = -3.0e38f;
        }
      }
      // tile max via max3 nests
      float p0 = max3f(s0[0], s0[1], s0[2]);
      float p1 = max3f(s0[3], s0[4], s0[5]);
      float p2 = max3f(s0[6], s0[7], s0[8]);
      float p3 = max3f(s0[9], s0[10], s0[11]);
      float p4 = max3f(s0[12], s0[13], s0[14]);
      float p5 = max3f(s1[0], s1[1], s1[2]);
      float p6 = max3f(s1[3], s1[4], s1[5]);
      float p7 = max3f(s1[6], s1[7], s1[8]);
      float p8 = max3f(s1[9], s1[10], s1[11]);
      float p9 = max3f(s1[12], s1[13], s1[14]);
      float pa = fmaxf(s0[15], s1[15]);
      float q0 = max3f(p0, p1, p2);
      float q1 = max3f(p3, p4, p5);
      float q2 = max3f(p6, p7, p8);
      float q3 = max3f(p9, pa, q0);
      float mtl = max3f(q1, q2, q3);
      float mt = fmaxf(mtl, __shfl_xor(mtl, 32));
      if (!__all(mt - m_run <= 8.0f)) {
        float mn = fmaxf(m_run, mt);
        float al = exp2fast(m_run - mn);
        m_run = mn;
#pragma unroll
        for (int r = 0; r < 16; ++r) { o0[r] *= al; o1[r] *= al; l16[r] *= al; }
      }
#pragma unroll
      for (int r = 0; r < 16; ++r) {
        s0[r] = exp2fast(s0[r] - m_run);
        s1[r] = exp2fast(s1[r] - m_run);
        l16[r] += s0[r] + s1[r];
      }
      short8 pb;
      const int swz = (col & 7);
#define PVMM(KS)                                                            \
  {                                                                         \
    const int ch = KS * 2 + hi;                                             \
    const int so = ((ch ^ swz) * 8);                                        \
    short8 va = *(const short8*)(V + col * 64 + so);                        \
    short8 vb = *(const short8*)(V + (32 + col) * 64 + so);                 \
    __builtin_amdgcn_s_setprio(1);                                          \
    o0 = __builtin_amdgcn_mfma_f32_32x32x16_bf16(va, pb, o0, 0, 0, 0);      \
    o1 = __builtin_amdgcn_mfma_f32_32x32x16_bf16(vb, pb, o1, 0, 0, 0);      \
    __builtin_amdgcn_s_setprio(0);                                          \
  }
      PACK(s0, 0, pb); PVMM(0)
      PACK(s0, 1, pb); PVMM(1)
      PACK(s1, 0, pb); PVMM(2)
      PACK(s1, 1, pb); PVMM(3)
#undef PVMM
    }
    asm volatile("s_waitcnt vmcnt(0)" ::: "memory");
    __syncthreads();
  }

  // deferred l reduction
  float l4[4];
#pragma unroll
  for (int r = 0; r < 4; ++r)
    l4[r] = (l16[4 * r] + l16[4 * r + 1]) + (l16[4 * r + 2] + l16[4 * r + 3]);
  float lsum = (l4[0] + l4[1]) + (l4[2] + l4[3]);
  float l_run = lsum + __shfl_xor(lsum, 32);
  const float inv = 1.f / l_run;
  ushort_t* obase = attn + ((size_t)b * TT + qg) * 2048 + h * 64;
#pragma unroll
  for (int g4 = 0; g4 < 4; ++g4) {
    int d = g4 * 8 + hi * 4;
    uint2v u2v;
    u2v[0] = cvtpk(o0[4 * g4 + 0] * inv, o0[4 * g4 + 1] * inv);
    u2v[1] = cvtpk(o0[4 * g4 + 2] * inv, o0[4 * g4 + 3] * inv);
    *(uint2v*)(obase + d) = u2v;
    uint2v u2b;
    u2b[0] = cvtpk(o1[4 * g4 + 0] * inv, o1[4 * g4 + 1] * inv);
    u2b[1] = cvtpk(o1[4 * g4 + 2] * inv, o1[4 * g4 + 3] * inv);
    *(uint2v*)(obase + 32 + d) = u2b;
  }
}

extern "C" void kernel_launch(void* const* d_in, const int* in_sizes, int n_in,
                              void* d_out, int out_size, void* d_ws, size_t ws_size,
                              hipStream_t stream) {
  (void)in_sizes; (void)n_in; (void)out_size; (void)ws_size;
  const float* x    = (const float*)d_in[0];
  const float* cosT = (const float*)d_in[1];
  const float* sinT = (const float*)d_in[2];
  const float* Wq   = (const float*)d_in[4];
  const float* Wk   = (const float*)d_in[5];
  const float* Wv   = (const float*)d_in[6];
  const float* Wo   = (const float*)d_in[7];

  float* outF   = (float*)d_out;
  float* kcache = outF + (size_t)8388608;             // B*T*C
  float* vcache = kcache + (size_t)2097152;           // B*T*G*D

  uint8_t* ws = (uint8_t*)d_ws;
  s8*       xq     = (s8*)(ws);
  float*    xs     = (float*)(ws + 8388608);
  float*    wqs    = (float*)(ws + 8388608 + 65536);
  float*    wos    = (float*)(ws + 8388608 + 131072);
  float*    as_s   = (float*)(ws + 8388608 + 196608);
  ushort_t* vt_ws  = (ushort_t*)(ws + 9437184);
  ushort_t* wqkvT  = (ushort_t*)(ws + 16777216);
  ushort_t* attn_ws= (ushort_t*)(ws + 16777216);
  s8*       wq_q   = (s8*)(ws + 35651584);
  ushort_t* q_ws   = (ushort_t*)(ws + 41943040);
  s8*       aq     = (s8*)(ws + 41943040);
  ushort_t* k_ws   = (ushort_t*)(ws + 58720256);
  ushort_t* v_ws   = (ushort_t*)(ws + 62914560);
  ushort_t* woT    = (ushort_t*)(ws + 67108864);
  s8*       wo_q   = (s8*)(ws + 75497472);

  prep1_kernel<<<14336, 256, 0, stream>>>(x, xq, xs, Wq, Wk, Wv, Wo, wqkvT, woT);
  wqall_kernel<<<5120, 256, 0, stream>>>(wqkvT, woT, wq_q, wo_q, wqs, wos);

  gemmq_kernel<0, 192><<<512, 512, 0, stream>>>(xq, wq_q, xs, wqs, cosT, sinT,
                                                q_ws, k_ws, v_ws, kcache, vcache,
                                                nullptr);
  vtrans_kernel<<<dim3(32, 16), 256, 0, stream>>>(v_ws, vt_ws);
  attn_kernel<<<1024, 256, 0, stream>>>(q_ws, k_ws, vt_ws, attn_ws);
  wq_kernel<<<4096, 256, 0, stream>>>(attn_ws, aq, as_s);
  gemmq_kernel<1, 128><<<512, 512, 0, stream>>>(aq, wo_q, as_s, wos, nullptr, nullptr,
                                                nullptr, nullptr, nullptr, nullptr,
                                                nullptr, outF);
}